// Round 14
// baseline (373.708 us; speedup 1.0000x reference)
//
#include <hip/hip_runtime.h>
#include <math.h>

#define NN 512   // set size / rows of feat_x
#define IN 512   // INPUT_DIM
#define HD 256   // HIDDEN_DIM
#define RD 256   // REP_DIM
#define SH 128   // SCORE_HIDDEN

// Branchless erf-GELU, A&S 7.1.26 (5-term) -- used in the g-MLP hidden layer.
__device__ __forceinline__ float gelu_fast(float x){
    const float z  = x * 0.70710678118654752f;
    const float az = fabsf(z);
    const float t  = __builtin_amdgcn_rcpf(fmaf(0.3275911f, az, 1.0f));
    float p = fmaf(1.061405429f, t, -1.453152027f);
    p = fmaf(p, t, 1.421413741f);
    p = fmaf(p, t, -0.284496736f);
    p = fmaf(p, t, 0.254829592f);
    p = p * t;
    const float e = __builtin_amdgcn_exp2f(z * z * -1.4426950408889634f);
    const float E = p * e;                        // erfc(|z|)
    const float one_plus_erf = (x >= 0.0f) ? (2.0f - E) : E;
    return 0.5f * x * one_plus_erf;
}

// u*(1+erf(u/sqrt2)) -- 0.5 folded into caller's weight. A&S 7.1.25 (3-term,
// |erf err| <= 2.5e-5 -> ~1.5e-5 logit error, far under threshold).
__device__ __forceinline__ float gelu2(float u){
    const float az = fabsf(u);
    const float tt = __builtin_amdgcn_rcpf(fmaf(0.3326725f, az, 1.0f));
    const float P  = fmaf(fmaf(0.7478556f, tt, -0.0958798f), tt, 0.3480242f) * tt;
    const float e2 = __builtin_amdgcn_exp2f(u * u * -0.72134752044448170f);
    const float Eq = P * e2;                      // erfc(|u|/sqrt2)
    const float ope = (u >= 0.0f) ? (2.0f - Eq) : Eq;
    return u * ope;
}

// K_REP: fused g-MLP + score-net projections + row norms (r12's best-measured
// 4-row/512-thread body). 384 blocks (3 mats x 128 4-row groups). Also zeroes
// the fin ticket counters (block 0) -- stream order guarantees visibility.
__global__ __launch_bounds__(512) void k_rep(
    const float* __restrict__ fx, const float* __restrict__ fp, const float* __restrict__ fn,
    const float* __restrict__ w1, const float* __restrict__ b1,
    const float* __restrict__ w2, const float* __restrict__ b2,
    const float* __restrict__ s_w1,
    float* __restrict__ r_x, float* __restrict__ r_p, float* __restrict__ r_n,
    float* __restrict__ rT_p, float* __restrict__ rT_n,
    float* __restrict__ A_x, float* __restrict__ BT_p, float* __restrict__ BT_n,
    float* __restrict__ nx2, float* __restrict__ np2, float* __restrict__ nn2,
    int* __restrict__ cnt)
{
    __shared__ float xs[4][IN];        // 8 KB
    __shared__ float ps[8][4][HD];     // 32 KB partials (reused by all GEMM phases)
    __shared__ float hs[4][HD];        // 4 KB
    __shared__ float rloc[4][RD];      // 4 KB
    __shared__ float ab4[4][SH];       // 2 KB
    const int t = threadIdx.x;
    const int mat = blockIdx.x >> 7;
    const int row0 = (blockIdx.x & 127) << 2;
    const float* src = (mat==0) ? fx : (mat==1) ? fp : fn;

    if (blockIdx.x == 0 && t < 256) cnt[t] = 0;   // fin ticket counters

    {   // stage 4 feat rows: 512 float4s
        const int j = t >> 7, c4 = (t & 127) << 2;
        *(float4*)&xs[j][c4] = *(const float4*)&src[(row0+j)*IN + c4];
    }
    __syncthreads();

    const int cg = t & 63, s = t >> 6;   // 64 colgroups x 8 K-slices
    const int c0 = cg << 2;

    {   // GEMM1: K=512, slice [s*64, s*64+64)
        float4 acc[4];
        #pragma unroll
        for (int j=0;j<4;j++) acc[j] = make_float4(0.f,0.f,0.f,0.f);
        const float* wp = w1 + (s*64)*HD + c0;
        #pragma unroll 8
        for (int ii=0; ii<64; ii++){
            float4 w = *(const float4*)wp; wp += HD;
            const int i = s*64 + ii;
            #pragma unroll
            for (int j=0;j<4;j++){
                const float xv = xs[j][i];
                acc[j].x = fmaf(xv, w.x, acc[j].x);
                acc[j].y = fmaf(xv, w.y, acc[j].y);
                acc[j].z = fmaf(xv, w.z, acc[j].z);
                acc[j].w = fmaf(xv, w.w, acc[j].w);
            }
        }
        #pragma unroll
        for (int j=0;j<4;j++) *(float4*)&ps[s][j][c0] = acc[j];
    }
    __syncthreads();

    #pragma unroll
    for (int rep=0; rep<2; rep++){   // reduce + bias + GELU -> hs
        const int idx = rep*512 + t;
        const int j = idx >> 8, c = idx & 255;
        float v = b1[c];
        #pragma unroll
        for (int ss=0; ss<8; ss++) v += ps[ss][j][c];
        hs[j][c] = gelu_fast(v);
    }
    __syncthreads();

    {   // GEMM2: K=256, slice [s*32, s*32+32)
        float4 acc[4];
        #pragma unroll
        for (int j=0;j<4;j++) acc[j] = make_float4(0.f,0.f,0.f,0.f);
        const float* wp = w2 + (s*32)*RD + c0;
        #pragma unroll 8
        for (int ii=0; ii<32; ii++){
            float4 w = *(const float4*)wp; wp += RD;
            const int i = s*32 + ii;
            #pragma unroll
            for (int j=0;j<4;j++){
                const float xv = hs[j][i];
                acc[j].x = fmaf(xv, w.x, acc[j].x);
                acc[j].y = fmaf(xv, w.y, acc[j].y);
                acc[j].z = fmaf(xv, w.z, acc[j].z);
                acc[j].w = fmaf(xv, w.w, acc[j].w);
            }
        }
        #pragma unroll
        for (int j=0;j<4;j++) *(float4*)&ps[s][j][c0] = acc[j];
    }
    __syncthreads();

    float* rout = (mat==0) ? r_x : (mat==1) ? r_p : r_n;
    #pragma unroll
    for (int rep=0; rep<2; rep++){   // reduce + bias -> rloc + global r
        const int idx = rep*512 + t;
        const int j = idx >> 8, c = idx & 255;
        float v = b2[c];
        #pragma unroll
        for (int ss=0; ss<8; ss++) v += ps[ss][j][c];
        rloc[j][c] = v;
        rout[(row0+j)*RD + c] = v;
    }
    __syncthreads();   // rloc complete; ps free for reuse

    if (t < 256){   // squared row norms: waves 0..3 -> rows 0..3
        const int w = t >> 6, l = t & 63;
        float v = 0.f;
        #pragma unroll
        for (int q=0;q<4;q++){ const float e = rloc[w][l + 64*q]; v = fmaf(e,e,v); }
        #pragma unroll
        for (int off=32; off>=1; off>>=1) v += __shfl_xor(v, off);
        if (l==0){
            float* nrm = (mat==0) ? nx2 : (mat==1) ? np2 : nn2;
            nrm[row0 + w] = v;
        }
    }
    if (mat && t < 256){   // transposed rep copy rT[r][m], float4 across rows
        float* rT = (mat==1) ? rT_p : rT_n;
        float4 q = make_float4(rloc[0][t], rloc[1][t], rloc[2][t], rloc[3][t]);
        *(float4*)&rT[t*NN + row0] = q;
    }

    {   // score-net projection: 128 cols, K=256 in 16 slices of 16
        const int cg2 = t & 31, s2 = t >> 5;
        const int cc0 = cg2 << 2;
        const float sgn = (mat==0) ? -1.0f : 1.0f;
        const int base1 = (mat==0) ? 0 : 256;
        const float* p1 = s_w1 + (base1 + s2*16)*SH + cc0;
        const float* p3 = s_w1 + (512   + s2*16)*SH + cc0;
        float4 a[4];
        #pragma unroll
        for (int j=0;j<4;j++) a[j] = make_float4(0.f,0.f,0.f,0.f);
        #pragma unroll 8
        for (int ii=0; ii<16; ii++){
            float4 wa = *(const float4*)p1; p1 += SH;
            float4 wd = *(const float4*)p3; p3 += SH;
            float4 w;
            w.x = fmaf(sgn, wd.x, wa.x);
            w.y = fmaf(sgn, wd.y, wa.y);
            w.z = fmaf(sgn, wd.z, wa.z);
            w.w = fmaf(sgn, wd.w, wa.w);
            const int i = s2*16 + ii;
            #pragma unroll
            for (int j=0;j<4;j++){
                const float xv = rloc[j][i];
                a[j].x = fmaf(xv, w.x, a[j].x);
                a[j].y = fmaf(xv, w.y, a[j].y);
                a[j].z = fmaf(xv, w.z, a[j].z);
                a[j].w = fmaf(xv, w.w, a[j].w);
            }
        }
        float* psf = &ps[0][0][0];   // reuse as [16][4][128]
        #pragma unroll
        for (int j=0;j<4;j++) *(float4*)&psf[(s2*4 + j)*SH + cc0] = a[j];
    }
    __syncthreads();

    {   // reduce 16 slices: 4 rows x 128 cols = 512 outputs
        const float* psf = &ps[0][0][0];
        const int j = t >> 7, c = t & 127;
        float v = 0.f;
        #pragma unroll
        for (int ss=0; ss<16; ss++) v += psf[(ss*4 + j)*SH + c];
        if (mat==0) A_x[(row0+j)*SH + c] = v;
        else        ab4[j][c] = v;
    }
    __syncthreads();
    if (mat && t < 128){   // BT[k][m], float4 across rows
        float* BT = (mat==1) ? BT_p : BT_n;
        float4 q = make_float4(ab4[0][t], ab4[1][t], ab4[2][t], ab4[3][t]);
        *(float4*)&BT[t*NN + row0] = q;
    }
}

// K_SD: distances + logits + exp + fused partial einsum + ATOMIC-TICKET fin
// tail. 2048 blocks (set x 256 2-row ntiles x 4 128-m mtiles) x 256 thr.
// Each n-pair has 8 producer blocks (2 set x 4 mt); the 8th to finish
// (atomicAdd ticket) performs that n-pair's normalize + out-projection.
// No deadlock: producers complete ALL work before ticketing.
__global__ __launch_bounds__(256) void k_sd(
    const float* __restrict__ r_x, const float* __restrict__ rT_p, const float* __restrict__ rT_n,
    const float* __restrict__ A_x, const float* __restrict__ BT_p, const float* __restrict__ BT_n,
    const float* __restrict__ r_p, const float* __restrict__ r_n,
    const float* __restrict__ nx2, const float* __restrict__ np2, const float* __restrict__ nn2,
    const float* __restrict__ s_w1, const float* __restrict__ s_b1,
    const float* __restrict__ s_w2, const float* __restrict__ out_w,
    float* __restrict__ psum, float* __restrict__ Spart,
    int* __restrict__ cnt, float* __restrict__ out)
{
    __shared__ float2 xs2[RD];        // 2 KB: {x0,x1}[r]
    __shared__ float4 cmb[SH];        // 2 KB: {A0+b1, A1+b1, wn, 0.5*w2}
    __shared__ float pda[2][128];     // stride-4B partials (conflict-free)
    __shared__ float pdb[2][128];
    __shared__ float ny2v[128];
    __shared__ float2 evb[128];       // 1 KB: per-m {ev0, ev1}
    __shared__ float ssum[2][2];
    __shared__ float dv[2][RD];       // 2 KB (fin tail)
    __shared__ int ticket;
    const int t = threadIdx.x;
    const int set = blockIdx.x >> 10;
    const int rem = blockIdx.x & 1023;
    const int np = rem >> 2;          // n-pair index [0,256)
    const int n0 = np << 1;
    const int mt = rem & 3;
    const int mbase = mt << 7;
    const int tm = t & 127, kh = t >> 7;   // kh uniform per wave
    const int m = mbase + tm;
    const float* yT = set ? rT_n : rT_p;
    const float* BT = set ? BT_n : BT_p;

    xs2[t] = make_float2(r_x[n0*RD + t], r_x[(n0+1)*RD + t]);
    if (t < SH){
        const float b1v = s_b1[t];
        cmb[t] = make_float4(A_x[n0*SH + t] + b1v,
                             A_x[(n0+1)*SH + t] + b1v,
                             s_w1[768*SH + t],
                             0.5f * s_w2[t]);
        ny2v[t] = (set ? nn2 : np2)[mbase + t];
    }
    const float nxa = nx2[n0];
    const float nxb = nx2[n0 + 1];
    __syncthreads();

    // phase 1: dots over this wave's r-half (coalesced column-major loads)
    float d0=0.f, d1=0.f;
    {
        const float* yp = yT + (kh << 7)*NN + m;
        #pragma unroll 16
        for (int rr=0; rr<128; rr++){
            const float y = yp[rr*NN];
            const float2 xv = xs2[(kh << 7) + rr];
            d0 = fmaf(xv.x, y, d0);
            d1 = fmaf(xv.y, y, d1);
        }
    }
    pda[kh][tm] = d0; pdb[kh][tm] = d1;
    __syncthreads();
    d0 += pda[1-kh][tm]; d1 += pdb[1-kh][tm];
    const float nyc = ny2v[tm];
    const float dn0 = sqrtf(fmaxf(fmaf(-2.f, d0, nxa + nyc), 0.f));
    const float dn1 = sqrtf(fmaxf(fmaf(-2.f, d1, nxb + nyc), 0.f));

    // phase 2: logits over this wave's k-half (coalesced BT loads)
    float acc0 = 0.f, acc1 = 0.f;
    {
        const float* bp = BT + (kh << 6)*NN + m;
        #pragma unroll 4
        for (int kk=0; kk<64; kk++){
            const float b = bp[kk*NN];
            const float4 c = cmb[(kh << 6) + kk];
            const float u0 = fmaf(dn0, c.z, c.x + b);
            const float u1 = fmaf(dn1, c.z, c.y + b);
            acc0 = fmaf(c.w, gelu2(u0), acc0);
            acc1 = fmaf(c.w, gelu2(u1), acc1);
        }
    }
    __syncthreads();                       // partner done reading phase-1 pd
    pda[kh][tm] = acc0; pdb[kh][tm] = acc1;
    __syncthreads();
    if (kh == 0){
        // s_b2 omitted (softmax shift-invariant); no max pass (logits O(1))
        const float ev0 = __builtin_amdgcn_exp2f((acc0 + pda[1][tm]) * 1.4426950408889634f);
        const float ev1 = __builtin_amdgcn_exp2f((acc1 + pdb[1][tm]) * 1.4426950408889634f);
        evb[tm] = make_float2(ev0, ev1);
        float v0 = ev0, v1 = ev1;
        #pragma unroll
        for (int off=32; off>=1; off>>=1){ v0 += __shfl_xor(v0, off); v1 += __shfl_xor(v1, off); }
        if ((t & 63) == 0){
            ssum[tm >> 6][0] = v0;
            ssum[tm >> 6][1] = v1;
        }
    }
    __syncthreads();
    if (t < 2)
        Spart[(set*4 + mt)*NN + n0 + t] = ssum[0][t] + ssum[1][t];

    // fused partial einsum: psum[set][mt][n0+j][c] = Sum_{m in tile} ev_j * r_y[m][c]
    {
        const float* ry = (set ? r_n : r_p) + mbase*RD + t;   // coalesced in c=t
        float a0 = 0.f, a1 = 0.f;
        #pragma unroll 8
        for (int mm=0; mm<128; mm++){
            const float rv = ry[mm*RD];
            const float2 w = evb[mm];        // ds_read_b64 broadcast
            a0 = fmaf(w.x, rv, a0);
            a1 = fmaf(w.y, rv, a1);
        }
        float* P = psum + ((set*4 + mt)*NN + n0)*RD;
        P[t]      = a0;
        P[RD + t] = a1;
    }

    // ===== atomic-ticket fin tail: 8th arrival for this n-pair finishes it =====
    __threadfence();                       // release psum/Spart writes
    if (t == 0) ticket = atomicAdd(&cnt[np], 1);
    __syncthreads();
    if (ticket == 7){
        __threadfence();                   // acquire other producers' writes
        #pragma unroll
        for (int rep=0; rep<2; rep++){     // dv: 512 entries, 2/thread
            const int idx = rep*256 + t;
            const int j = idx >> 8, c = idx & 255;
            const int n = n0 + j;
            float Sp = 0.f, Sn = 0.f;
            #pragma unroll
            for (int q=0;q<4;q++){
                Sp += Spart[q*NN + n];
                Sn += Spart[(4+q)*NN + n];
            }
            float vp = 0.f, vn = 0.f;
            #pragma unroll
            for (int q=0;q<4;q++){
                vp += psum[(q*NN + n)*RD + c];
                vn += psum[((4+q)*NN + n)*RD + c];
            }
            dv[j][c] = vp * (1.0f/Sp) - vn * (1.0f/Sn);
        }
        __syncthreads();
        #pragma unroll
        for (int q=0; q<4; q++){           // out: 2 rows x 512 cols, 4/thread
            const int j = q >> 1;
            const int col = ((q & 1) << 8) + t;
            float o = 0.f;
            const float* wo = out_w + col;
            #pragma unroll 8
            for (int r=0; r<RD; r++){ o = fmaf(dv[j][r], *wo, o); wo += IN; }
            out[(n0+j)*IN + col] = o;
        }
    }
}

extern "C" void kernel_launch(void* const* d_in, const int* in_sizes, int n_in,
                              void* d_out, int out_size, void* d_ws, size_t ws_size,
                              hipStream_t stream)
{
    const float* fx  = (const float*)d_in[0];
    const float* fp  = (const float*)d_in[1];
    const float* fn  = (const float*)d_in[2];
    const float* gw1 = (const float*)d_in[3];
    const float* gb1 = (const float*)d_in[4];
    const float* gw2 = (const float*)d_in[5];
    const float* gb2 = (const float*)d_in[6];
    const float* ow  = (const float*)d_in[7];
    const float* sw1 = (const float*)d_in[8];
    const float* sb1 = (const float*)d_in[9];
    const float* sw2 = (const float*)d_in[10];
    float* out = (float*)d_out;

    float* ws   = (float*)d_ws;
    float* r_x  = ws;               // 512*256 row-major
    float* r_p  = r_x  + 131072;
    float* r_n  = r_p  + 131072;
    float* rT_p = r_n  + 131072;    // 256*512 column-major
    float* rT_n = rT_p + 131072;
    float* A_x  = rT_n + 131072;    // 512*128 row-major [n][k]
    float* BT_p = A_x  + 65536;     // 128*512 column-major [k][m]
    float* BT_n = BT_p + 65536;
    float* Spar = BT_n + 65536;     // 2*4*512
    float* nx2  = Spar + 4096;      // 512
    float* np2  = nx2  + 512;
    float* nn2  = np2  + 512;
    float* psum = nn2  + 512;       // 2*4*512*256 (4 MB)
    int*   cnt  = (int*)(psum + 1048576);   // 256 ticket counters

    hipLaunchKernelGGL(k_rep, dim3(384), dim3(512), 0, stream,
                       fx, fp, fn, gw1, gb1, gw2, gb2, sw1,
                       r_x, r_p, r_n, rT_p, rT_n, A_x, BT_p, BT_n,
                       nx2, np2, nn2, cnt);
    hipLaunchKernelGGL(k_sd, dim3(2048), dim3(256), 0, stream,
                       r_x, rT_p, rT_n, A_x, BT_p, BT_n, r_p, r_n,
                       nx2, np2, nn2, sw1, sb1, sw2, ow,
                       psum, Spar, cnt, out);
}

// Round 15
// 158.989 us; speedup vs baseline: 2.3505x; 2.3505x over previous
//
#include <hip/hip_runtime.h>
#include <math.h>

#define NN 512   // set size / rows of feat_x
#define IN 512   // INPUT_DIM
#define HD 256   // HIDDEN_DIM
#define RD 256   // REP_DIM
#define SH 128   // SCORE_HIDDEN

// Branchless erf-GELU, A&S 7.1.26 (5-term) -- used in the g-MLP hidden layer.
__device__ __forceinline__ float gelu_fast(float x){
    const float z  = x * 0.70710678118654752f;
    const float az = fabsf(z);
    const float t  = __builtin_amdgcn_rcpf(fmaf(0.3275911f, az, 1.0f));
    float p = fmaf(1.061405429f, t, -1.453152027f);
    p = fmaf(p, t, 1.421413741f);
    p = fmaf(p, t, -0.284496736f);
    p = fmaf(p, t, 0.254829592f);
    p = p * t;
    const float e = __builtin_amdgcn_exp2f(z * z * -1.4426950408889634f);
    const float E = p * e;                        // erfc(|z|)
    const float one_plus_erf = (x >= 0.0f) ? (2.0f - E) : E;
    return 0.5f * x * one_plus_erf;
}

// u*(1+erf(u/sqrt2)) -- 0.5 folded into caller's weight. A&S 7.1.25 (3-term,
// |erf err| <= 2.5e-5 -> ~1.5e-5 logit error, far under threshold).
__device__ __forceinline__ float gelu2(float u){
    const float az = fabsf(u);
    const float tt = __builtin_amdgcn_rcpf(fmaf(0.3326725f, az, 1.0f));
    const float P  = fmaf(fmaf(0.7478556f, tt, -0.0958798f), tt, 0.3480242f) * tt;
    const float e2 = __builtin_amdgcn_exp2f(u * u * -0.72134752044448170f);
    const float Eq = P * e2;                      // erfc(|u|/sqrt2)
    const float ope = (u >= 0.0f) ? (2.0f - Eq) : Eq;
    return u * ope;
}

// K_REP: fused g-MLP + score-net projections + row norms. r12's best-measured
// 4-row/512-thread/384-block body (4 rows/block minimizes per-CU weight
// re-streaming: 768-block 2-row variant measured WORSE — r13).
__global__ __launch_bounds__(512) void k_rep(
    const float* __restrict__ fx, const float* __restrict__ fp, const float* __restrict__ fn,
    const float* __restrict__ w1, const float* __restrict__ b1,
    const float* __restrict__ w2, const float* __restrict__ b2,
    const float* __restrict__ s_w1,
    float* __restrict__ r_x, float* __restrict__ r_p, float* __restrict__ r_n,
    float* __restrict__ rT_p, float* __restrict__ rT_n,
    float* __restrict__ A_x, float* __restrict__ BT_p, float* __restrict__ BT_n,
    float* __restrict__ nx2, float* __restrict__ np2, float* __restrict__ nn2)
{
    __shared__ float xs[4][IN];        // 8 KB
    __shared__ float ps[8][4][HD];     // 32 KB partials (reused by all GEMM phases)
    __shared__ float hs[4][HD];        // 4 KB
    __shared__ float rloc[4][RD];      // 4 KB
    __shared__ float ab4[4][SH];       // 2 KB
    const int t = threadIdx.x;
    const int mat = blockIdx.x >> 7;
    const int row0 = (blockIdx.x & 127) << 2;
    const float* src = (mat==0) ? fx : (mat==1) ? fp : fn;

    {   // stage 4 feat rows: 512 float4s
        const int j = t >> 7, c4 = (t & 127) << 2;
        *(float4*)&xs[j][c4] = *(const float4*)&src[(row0+j)*IN + c4];
    }
    __syncthreads();

    const int cg = t & 63, s = t >> 6;   // 64 colgroups x 8 K-slices
    const int c0 = cg << 2;

    {   // GEMM1: K=512, slice [s*64, s*64+64)
        float4 acc[4];
        #pragma unroll
        for (int j=0;j<4;j++) acc[j] = make_float4(0.f,0.f,0.f,0.f);
        const float* wp = w1 + (s*64)*HD + c0;
        #pragma unroll 8
        for (int ii=0; ii<64; ii++){
            float4 w = *(const float4*)wp; wp += HD;
            const int i = s*64 + ii;
            #pragma unroll
            for (int j=0;j<4;j++){
                const float xv = xs[j][i];
                acc[j].x = fmaf(xv, w.x, acc[j].x);
                acc[j].y = fmaf(xv, w.y, acc[j].y);
                acc[j].z = fmaf(xv, w.z, acc[j].z);
                acc[j].w = fmaf(xv, w.w, acc[j].w);
            }
        }
        #pragma unroll
        for (int j=0;j<4;j++) *(float4*)&ps[s][j][c0] = acc[j];
    }
    __syncthreads();

    #pragma unroll
    for (int rep=0; rep<2; rep++){   // reduce + bias + GELU -> hs
        const int idx = rep*512 + t;
        const int j = idx >> 8, c = idx & 255;
        float v = b1[c];
        #pragma unroll
        for (int ss=0; ss<8; ss++) v += ps[ss][j][c];
        hs[j][c] = gelu_fast(v);
    }
    __syncthreads();

    {   // GEMM2: K=256, slice [s*32, s*32+32)
        float4 acc[4];
        #pragma unroll
        for (int j=0;j<4;j++) acc[j] = make_float4(0.f,0.f,0.f,0.f);
        const float* wp = w2 + (s*32)*RD + c0;
        #pragma unroll 8
        for (int ii=0; ii<32; ii++){
            float4 w = *(const float4*)wp; wp += RD;
            const int i = s*32 + ii;
            #pragma unroll
            for (int j=0;j<4;j++){
                const float xv = hs[j][i];
                acc[j].x = fmaf(xv, w.x, acc[j].x);
                acc[j].y = fmaf(xv, w.y, acc[j].y);
                acc[j].z = fmaf(xv, w.z, acc[j].z);
                acc[j].w = fmaf(xv, w.w, acc[j].w);
            }
        }
        #pragma unroll
        for (int j=0;j<4;j++) *(float4*)&ps[s][j][c0] = acc[j];
    }
    __syncthreads();

    float* rout = (mat==0) ? r_x : (mat==1) ? r_p : r_n;
    #pragma unroll
    for (int rep=0; rep<2; rep++){   // reduce + bias -> rloc + global r
        const int idx = rep*512 + t;
        const int j = idx >> 8, c = idx & 255;
        float v = b2[c];
        #pragma unroll
        for (int ss=0; ss<8; ss++) v += ps[ss][j][c];
        rloc[j][c] = v;
        rout[(row0+j)*RD + c] = v;
    }
    __syncthreads();   // rloc complete; ps free for reuse

    if (t < 256){   // squared row norms: waves 0..3 -> rows 0..3
        const int w = t >> 6, l = t & 63;
        float v = 0.f;
        #pragma unroll
        for (int q=0;q<4;q++){ const float e = rloc[w][l + 64*q]; v = fmaf(e,e,v); }
        #pragma unroll
        for (int off=32; off>=1; off>>=1) v += __shfl_xor(v, off);
        if (l==0){
            float* nrm = (mat==0) ? nx2 : (mat==1) ? np2 : nn2;
            nrm[row0 + w] = v;
        }
    }
    if (mat && t < 256){   // transposed rep copy rT[r][m], float4 across rows
        float* rT = (mat==1) ? rT_p : rT_n;
        float4 q = make_float4(rloc[0][t], rloc[1][t], rloc[2][t], rloc[3][t]);
        *(float4*)&rT[t*NN + row0] = q;
    }

    {   // score-net projection: 128 cols, K=256 in 16 slices of 16
        const int cg2 = t & 31, s2 = t >> 5;
        const int cc0 = cg2 << 2;
        const float sgn = (mat==0) ? -1.0f : 1.0f;
        const int base1 = (mat==0) ? 0 : 256;
        const float* p1 = s_w1 + (base1 + s2*16)*SH + cc0;
        const float* p3 = s_w1 + (512   + s2*16)*SH + cc0;
        float4 a[4];
        #pragma unroll
        for (int j=0;j<4;j++) a[j] = make_float4(0.f,0.f,0.f,0.f);
        #pragma unroll 8
        for (int ii=0; ii<16; ii++){
            float4 wa = *(const float4*)p1; p1 += SH;
            float4 wd = *(const float4*)p3; p3 += SH;
            float4 w;
            w.x = fmaf(sgn, wd.x, wa.x);
            w.y = fmaf(sgn, wd.y, wa.y);
            w.z = fmaf(sgn, wd.z, wa.z);
            w.w = fmaf(sgn, wd.w, wa.w);
            const int i = s2*16 + ii;
            #pragma unroll
            for (int j=0;j<4;j++){
                const float xv = rloc[j][i];
                a[j].x = fmaf(xv, w.x, a[j].x);
                a[j].y = fmaf(xv, w.y, a[j].y);
                a[j].z = fmaf(xv, w.z, a[j].z);
                a[j].w = fmaf(xv, w.w, a[j].w);
            }
        }
        float* psf = &ps[0][0][0];   // reuse as [16][4][128]
        #pragma unroll
        for (int j=0;j<4;j++) *(float4*)&psf[(s2*4 + j)*SH + cc0] = a[j];
    }
    __syncthreads();

    {   // reduce 16 slices: 4 rows x 128 cols = 512 outputs
        const float* psf = &ps[0][0][0];
        const int j = t >> 7, c = t & 127;
        float v = 0.f;
        #pragma unroll
        for (int ss=0; ss<16; ss++) v += psf[(ss*4 + j)*SH + c];
        if (mat==0) A_x[(row0+j)*SH + c] = v;
        else        ab4[j][c] = v;
    }
    __syncthreads();
    if (mat && t < 128){   // BT[k][m], float4 across rows
        float* BT = (mat==1) ? BT_p : BT_n;
        float4 q = make_float4(ab4[0][t], ab4[1][t], ab4[2][t], ab4[3][t]);
        *(float4*)&BT[t*NN + row0] = q;
    }
}

// K_SD: distances + logits + exp + fused partial einsum (r13's 50.4 us body).
// 2048 blocks (set x 256 2-row ntiles x 4 128-m mtiles) x 256 thr = 8/CU.
// Norms imported from k_rep; 3-term gelu; wave-level k-split; all coalesced.
__global__ __launch_bounds__(256) void k_sd(
    const float* __restrict__ r_x, const float* __restrict__ rT_p, const float* __restrict__ rT_n,
    const float* __restrict__ A_x, const float* __restrict__ BT_p, const float* __restrict__ BT_n,
    const float* __restrict__ r_p, const float* __restrict__ r_n,
    const float* __restrict__ nx2, const float* __restrict__ np2, const float* __restrict__ nn2,
    const float* __restrict__ s_w1, const float* __restrict__ s_b1,
    const float* __restrict__ s_w2,
    float* __restrict__ psum, float* __restrict__ Spart)
{
    __shared__ float2 xs2[RD];        // 2 KB: {x0,x1}[r]
    __shared__ float4 cmb[SH];        // 2 KB: {A0+b1, A1+b1, wn, 0.5*w2}
    __shared__ float pda[2][128];     // stride-4B partials (conflict-free)
    __shared__ float pdb[2][128];
    __shared__ float ny2v[128];
    __shared__ float2 evb[128];       // 1 KB: per-m {ev0, ev1}
    __shared__ float ssum[2][2];
    const int t = threadIdx.x;
    const int set = blockIdx.x >> 10;
    const int rem = blockIdx.x & 1023;
    const int n0 = (rem >> 2) << 1;
    const int mt = rem & 3;
    const int mbase = mt << 7;
    const int tm = t & 127, kh = t >> 7;   // kh uniform per wave
    const int m = mbase + tm;
    const float* yT = set ? rT_n : rT_p;
    const float* BT = set ? BT_n : BT_p;

    xs2[t] = make_float2(r_x[n0*RD + t], r_x[(n0+1)*RD + t]);
    if (t < SH){
        const float b1v = s_b1[t];
        cmb[t] = make_float4(A_x[n0*SH + t] + b1v,
                             A_x[(n0+1)*SH + t] + b1v,
                             s_w1[768*SH + t],
                             0.5f * s_w2[t]);
        ny2v[t] = (set ? nn2 : np2)[mbase + t];
    }
    const float nxa = nx2[n0];         // wave-uniform -> scalar loads
    const float nxb = nx2[n0 + 1];
    __syncthreads();

    // phase 1: dots over this wave's r-half (coalesced column-major loads)
    float d0=0.f, d1=0.f;
    {
        const float* yp = yT + (kh << 7)*NN + m;
        #pragma unroll 16
        for (int rr=0; rr<128; rr++){
            const float y = yp[rr*NN];
            const float2 xv = xs2[(kh << 7) + rr];
            d0 = fmaf(xv.x, y, d0);
            d1 = fmaf(xv.y, y, d1);
        }
    }
    pda[kh][tm] = d0; pdb[kh][tm] = d1;
    __syncthreads();
    d0 += pda[1-kh][tm]; d1 += pdb[1-kh][tm];
    const float nyc = ny2v[tm];
    const float dn0 = sqrtf(fmaxf(fmaf(-2.f, d0, nxa + nyc), 0.f));
    const float dn1 = sqrtf(fmaxf(fmaf(-2.f, d1, nxb + nyc), 0.f));

    // phase 2: logits over this wave's k-half (coalesced BT loads)
    float acc0 = 0.f, acc1 = 0.f;
    {
        const float* bp = BT + (kh << 6)*NN + m;
        #pragma unroll 4
        for (int kk=0; kk<64; kk++){
            const float b = bp[kk*NN];
            const float4 c = cmb[(kh << 6) + kk];
            const float u0 = fmaf(dn0, c.z, c.x + b);
            const float u1 = fmaf(dn1, c.z, c.y + b);
            acc0 = fmaf(c.w, gelu2(u0), acc0);
            acc1 = fmaf(c.w, gelu2(u1), acc1);
        }
    }
    __syncthreads();                       // partner done reading phase-1 pd
    pda[kh][tm] = acc0; pdb[kh][tm] = acc1;
    __syncthreads();
    if (kh == 0){
        // s_b2 omitted (softmax shift-invariant); no max pass (logits O(1))
        const float ev0 = __builtin_amdgcn_exp2f((acc0 + pda[1][tm]) * 1.4426950408889634f);
        const float ev1 = __builtin_amdgcn_exp2f((acc1 + pdb[1][tm]) * 1.4426950408889634f);
        evb[tm] = make_float2(ev0, ev1);
        float v0 = ev0, v1 = ev1;
        #pragma unroll
        for (int off=32; off>=1; off>>=1){ v0 += __shfl_xor(v0, off); v1 += __shfl_xor(v1, off); }
        if ((t & 63) == 0){
            ssum[tm >> 6][0] = v0;
            ssum[tm >> 6][1] = v1;
        }
    }
    __syncthreads();
    if (t < 2)
        Spart[(set*4 + mt)*NN + n0 + t] = ssum[0][t] + ssum[1][t];

    // fused partial einsum: psum[set][mt][n0+j][c] = Sum_{m in tile} ev_j * r_y[m][c]
    {
        const float* ry = (set ? r_n : r_p) + mbase*RD + t;   // coalesced in c=t
        float a0 = 0.f, a1 = 0.f;
        #pragma unroll 8
        for (int mm=0; mm<128; mm++){
            const float rv = ry[mm*RD];
            const float2 w = evb[mm];        // ds_read_b64 broadcast
            a0 = fmaf(w.x, rv, a0);
            a1 = fmaf(w.y, rv, a1);
        }
        float* P = psum + ((set*4 + mt)*NN + n0)*RD;
        P[t]      = a0;
        P[RD + t] = a1;
    }
}

// K_FIN: dv = Sum_mt psum_p/Sp - Sum_mt psum_n/Sn; out = dv @ out_w.
// 1024 blocks (256 n-pairs x 4 col-tiles) x 256 thr = 4/CU, 16 waves/CU.
__global__ __launch_bounds__(256) void k_fin(
    const float* __restrict__ psum, const float* __restrict__ Spart,
    const float* __restrict__ out_w, float* __restrict__ out)
{
    __shared__ float dv[2][RD];   // 2 KB
    const int t = threadIdx.x;
    const int np = blockIdx.x >> 2, ct = blockIdx.x & 3;
    const int n0 = np << 1;
    const int cb = ct << 7;

    #pragma unroll
    for (int rep=0; rep<2; rep++){   // dv: 512 entries, 2/thread
        const int idx = rep*256 + t;
        const int j = idx >> 8, c = idx & 255;
        const int n = n0 + j;
        float Sp = 0.f, Sn = 0.f;
        #pragma unroll
        for (int q=0;q<4;q++){
            Sp += Spart[q*NN + n];
            Sn += Spart[(4+q)*NN + n];
        }
        float vp = 0.f, vn = 0.f;
        #pragma unroll
        for (int q=0;q<4;q++){
            vp += psum[(q*NN + n)*RD + c];
            vn += psum[((4+q)*NN + n)*RD + c];
        }
        dv[j][c] = vp * (1.0f/Sp) - vn * (1.0f/Sn);
    }
    __syncthreads();

    {   // out[j][cb+cc] = Sum_r dv[j][r]*out_w[r][cb+cc]
        const int j = t >> 7, cc = t & 127;
        const int col = cb + cc;
        float o = 0.f;
        const float* wo = out_w + col;
        #pragma unroll 8
        for (int r=0; r<RD; r++){ o = fmaf(dv[j][r], *wo, o); wo += IN; }
        out[(n0+j)*IN + col] = o;
    }
}

extern "C" void kernel_launch(void* const* d_in, const int* in_sizes, int n_in,
                              void* d_out, int out_size, void* d_ws, size_t ws_size,
                              hipStream_t stream)
{
    const float* fx  = (const float*)d_in[0];
    const float* fp  = (const float*)d_in[1];
    const float* fn  = (const float*)d_in[2];
    const float* gw1 = (const float*)d_in[3];
    const float* gb1 = (const float*)d_in[4];
    const float* gw2 = (const float*)d_in[5];
    const float* gb2 = (const float*)d_in[6];
    const float* ow  = (const float*)d_in[7];
    const float* sw1 = (const float*)d_in[8];
    const float* sb1 = (const float*)d_in[9];
    const float* sw2 = (const float*)d_in[10];
    float* out = (float*)d_out;

    float* ws   = (float*)d_ws;
    float* r_x  = ws;               // 512*256 row-major
    float* r_p  = r_x  + 131072;
    float* r_n  = r_p  + 131072;
    float* rT_p = r_n  + 131072;    // 256*512 column-major
    float* rT_n = rT_p + 131072;
    float* A_x  = rT_n + 131072;    // 512*128 row-major [n][k]
    float* BT_p = A_x  + 65536;     // 128*512 column-major [k][m]
    float* BT_n = BT_p + 65536;
    float* Spar = BT_n + 65536;     // 2*4*512
    float* nx2  = Spar + 4096;      // 512
    float* np2  = nx2  + 512;
    float* nn2  = np2  + 512;
    float* psum = nn2  + 512;       // 2*4*512*256 (4 MB)

    hipLaunchKernelGGL(k_rep, dim3(384), dim3(512), 0, stream,
                       fx, fp, fn, gw1, gb1, gw2, gb2, sw1,
                       r_x, r_p, r_n, rT_p, rT_n, A_x, BT_p, BT_n,
                       nx2, np2, nn2);
    hipLaunchKernelGGL(k_sd, dim3(2048), dim3(256), 0, stream,
                       r_x, rT_p, rT_n, A_x, BT_p, BT_n, r_p, r_n,
                       nx2, np2, nn2, sw1, sb1, sw2, psum, Spar);
    hipLaunchKernelGGL(k_fin, dim3(1024), dim3(256), 0, stream,
                       psum, Spar, ow, out);
}

// Round 16
// 156.061 us; speedup vs baseline: 2.3946x; 1.0188x over previous
//
#include <hip/hip_runtime.h>
#include <math.h>

#define NN 512   // set size / rows of feat_x
#define IN 512   // INPUT_DIM
#define HD 256   // HIDDEN_DIM
#define RD 256   // REP_DIM
#define SH 128   // SCORE_HIDDEN

// Branchless erf-GELU, A&S 7.1.26 (5-term) -- used in the g-MLP hidden layer.
__device__ __forceinline__ float gelu_fast(float x){
    const float z  = x * 0.70710678118654752f;
    const float az = fabsf(z);
    const float t  = __builtin_amdgcn_rcpf(fmaf(0.3275911f, az, 1.0f));
    float p = fmaf(1.061405429f, t, -1.453152027f);
    p = fmaf(p, t, 1.421413741f);
    p = fmaf(p, t, -0.284496736f);
    p = fmaf(p, t, 0.254829592f);
    p = p * t;
    const float e = __builtin_amdgcn_exp2f(z * z * -1.4426950408889634f);
    const float E = p * e;                        // erfc(|z|)
    const float one_plus_erf = (x >= 0.0f) ? (2.0f - E) : E;
    return 0.5f * x * one_plus_erf;
}

// u*(1+erf(u/sqrt2)) -- 0.5 folded into caller's weight. A&S 7.1.25 (3-term).
__device__ __forceinline__ float gelu2(float u){
    const float az = fabsf(u);
    const float tt = __builtin_amdgcn_rcpf(fmaf(0.3326725f, az, 1.0f));
    const float P  = fmaf(fmaf(0.7478556f, tt, -0.0958798f), tt, 0.3480242f) * tt;
    const float e2 = __builtin_amdgcn_exp2f(u * u * -0.72134752044448170f);
    const float Eq = P * e2;                      // erfc(|u|/sqrt2)
    const float ope = (u >= 0.0f) ? (2.0f - Eq) : Eq;
    return u * ope;
}

// K_REP: fused g-MLP + score-net projections + row norms (verbatim r15 winner:
// 4-row/512-thread/384-block; 4 rows/block minimizes per-CU weight
// re-streaming -- 768-block 2-row variant measured WORSE, r13).
__global__ __launch_bounds__(512) void k_rep(
    const float* __restrict__ fx, const float* __restrict__ fp, const float* __restrict__ fn,
    const float* __restrict__ w1, const float* __restrict__ b1,
    const float* __restrict__ w2, const float* __restrict__ b2,
    const float* __restrict__ s_w1,
    float* __restrict__ r_x, float* __restrict__ r_p, float* __restrict__ r_n,
    float* __restrict__ rT_p, float* __restrict__ rT_n,
    float* __restrict__ A_x, float* __restrict__ BT_p, float* __restrict__ BT_n,
    float* __restrict__ nx2, float* __restrict__ np2, float* __restrict__ nn2)
{
    __shared__ float xs[4][IN];        // 8 KB
    __shared__ float ps[8][4][HD];     // 32 KB partials (reused by all GEMM phases)
    __shared__ float hs[4][HD];        // 4 KB
    __shared__ float rloc[4][RD];      // 4 KB
    __shared__ float ab4[4][SH];       // 2 KB
    const int t = threadIdx.x;
    const int mat = blockIdx.x >> 7;
    const int row0 = (blockIdx.x & 127) << 2;
    const float* src = (mat==0) ? fx : (mat==1) ? fp : fn;

    {   // stage 4 feat rows: 512 float4s
        const int j = t >> 7, c4 = (t & 127) << 2;
        *(float4*)&xs[j][c4] = *(const float4*)&src[(row0+j)*IN + c4];
    }
    __syncthreads();

    const int cg = t & 63, s = t >> 6;   // 64 colgroups x 8 K-slices
    const int c0 = cg << 2;

    {   // GEMM1: K=512, slice [s*64, s*64+64)
        float4 acc[4];
        #pragma unroll
        for (int j=0;j<4;j++) acc[j] = make_float4(0.f,0.f,0.f,0.f);
        const float* wp = w1 + (s*64)*HD + c0;
        #pragma unroll 8
        for (int ii=0; ii<64; ii++){
            float4 w = *(const float4*)wp; wp += HD;
            const int i = s*64 + ii;
            #pragma unroll
            for (int j=0;j<4;j++){
                const float xv = xs[j][i];
                acc[j].x = fmaf(xv, w.x, acc[j].x);
                acc[j].y = fmaf(xv, w.y, acc[j].y);
                acc[j].z = fmaf(xv, w.z, acc[j].z);
                acc[j].w = fmaf(xv, w.w, acc[j].w);
            }
        }
        #pragma unroll
        for (int j=0;j<4;j++) *(float4*)&ps[s][j][c0] = acc[j];
    }
    __syncthreads();

    #pragma unroll
    for (int rep=0; rep<2; rep++){   // reduce + bias + GELU -> hs
        const int idx = rep*512 + t;
        const int j = idx >> 8, c = idx & 255;
        float v = b1[c];
        #pragma unroll
        for (int ss=0; ss<8; ss++) v += ps[ss][j][c];
        hs[j][c] = gelu_fast(v);
    }
    __syncthreads();

    {   // GEMM2: K=256, slice [s*32, s*32+32)
        float4 acc[4];
        #pragma unroll
        for (int j=0;j<4;j++) acc[j] = make_float4(0.f,0.f,0.f,0.f);
        const float* wp = w2 + (s*32)*RD + c0;
        #pragma unroll 8
        for (int ii=0; ii<32; ii++){
            float4 w = *(const float4*)wp; wp += RD;
            const int i = s*32 + ii;
            #pragma unroll
            for (int j=0;j<4;j++){
                const float xv = hs[j][i];
                acc[j].x = fmaf(xv, w.x, acc[j].x);
                acc[j].y = fmaf(xv, w.y, acc[j].y);
                acc[j].z = fmaf(xv, w.z, acc[j].z);
                acc[j].w = fmaf(xv, w.w, acc[j].w);
            }
        }
        #pragma unroll
        for (int j=0;j<4;j++) *(float4*)&ps[s][j][c0] = acc[j];
    }
    __syncthreads();

    float* rout = (mat==0) ? r_x : (mat==1) ? r_p : r_n;
    #pragma unroll
    for (int rep=0; rep<2; rep++){   // reduce + bias -> rloc + global r
        const int idx = rep*512 + t;
        const int j = idx >> 8, c = idx & 255;
        float v = b2[c];
        #pragma unroll
        for (int ss=0; ss<8; ss++) v += ps[ss][j][c];
        rloc[j][c] = v;
        rout[(row0+j)*RD + c] = v;
    }
    __syncthreads();   // rloc complete; ps free for reuse

    if (t < 256){   // squared row norms: waves 0..3 -> rows 0..3
        const int w = t >> 6, l = t & 63;
        float v = 0.f;
        #pragma unroll
        for (int q=0;q<4;q++){ const float e = rloc[w][l + 64*q]; v = fmaf(e,e,v); }
        #pragma unroll
        for (int off=32; off>=1; off>>=1) v += __shfl_xor(v, off);
        if (l==0){
            float* nrm = (mat==0) ? nx2 : (mat==1) ? np2 : nn2;
            nrm[row0 + w] = v;
        }
    }
    if (mat && t < 256){   // transposed rep copy rT[r][m], float4 across rows
        float* rT = (mat==1) ? rT_p : rT_n;
        float4 q = make_float4(rloc[0][t], rloc[1][t], rloc[2][t], rloc[3][t]);
        *(float4*)&rT[t*NN + row0] = q;
    }

    {   // score-net projection: 128 cols, K=256 in 16 slices of 16
        const int cg2 = t & 31, s2 = t >> 5;
        const int cc0 = cg2 << 2;
        const float sgn = (mat==0) ? -1.0f : 1.0f;
        const int base1 = (mat==0) ? 0 : 256;
        const float* p1 = s_w1 + (base1 + s2*16)*SH + cc0;
        const float* p3 = s_w1 + (512   + s2*16)*SH + cc0;
        float4 a[4];
        #pragma unroll
        for (int j=0;j<4;j++) a[j] = make_float4(0.f,0.f,0.f,0.f);
        #pragma unroll 8
        for (int ii=0; ii<16; ii++){
            float4 wa = *(const float4*)p1; p1 += SH;
            float4 wd = *(const float4*)p3; p3 += SH;
            float4 w;
            w.x = fmaf(sgn, wd.x, wa.x);
            w.y = fmaf(sgn, wd.y, wa.y);
            w.z = fmaf(sgn, wd.z, wa.z);
            w.w = fmaf(sgn, wd.w, wa.w);
            const int i = s2*16 + ii;
            #pragma unroll
            for (int j=0;j<4;j++){
                const float xv = rloc[j][i];
                a[j].x = fmaf(xv, w.x, a[j].x);
                a[j].y = fmaf(xv, w.y, a[j].y);
                a[j].z = fmaf(xv, w.z, a[j].z);
                a[j].w = fmaf(xv, w.w, a[j].w);
            }
        }
        float* psf = &ps[0][0][0];   // reuse as [16][4][128]
        #pragma unroll
        for (int j=0;j<4;j++) *(float4*)&psf[(s2*4 + j)*SH + cc0] = a[j];
    }
    __syncthreads();

    {   // reduce 16 slices: 4 rows x 128 cols = 512 outputs
        const float* psf = &ps[0][0][0];
        const int j = t >> 7, c = t & 127;
        float v = 0.f;
        #pragma unroll
        for (int ss=0; ss<16; ss++) v += psf[(ss*4 + j)*SH + c];
        if (mat==0) A_x[(row0+j)*SH + c] = v;
        else        ab4[j][c] = v;
    }
    __syncthreads();
    if (mat && t < 128){   // BT[k][m], float4 across rows
        float* BT = (mat==1) ? BT_p : BT_n;
        float4 q = make_float4(ab4[0][t], ab4[1][t], ab4[2][t], ab4[3][t]);
        *(float4*)&BT[t*NN + row0] = q;
    }
}

// K_SD: distances + logits + exp + fused partial einsum, now 4 rows/thread.
// 1024 blocks (set x 128 4-row ntiles x 4 128-m mtiles) x 256 thr = 4/CU
// balanced. Wave-level k-split (waves 0,1 = low half; 2,3 = high half) keeps
// every global load coalesced; shared per-iteration costs (y, b, broadcasts)
// now serve 4 FMAs/gelus instead of 2. psum layout unchanged -> k_fin same.
__global__ __launch_bounds__(256) void k_sd(
    const float* __restrict__ r_x, const float* __restrict__ rT_p, const float* __restrict__ rT_n,
    const float* __restrict__ A_x, const float* __restrict__ BT_p, const float* __restrict__ BT_n,
    const float* __restrict__ r_p, const float* __restrict__ r_n,
    const float* __restrict__ nx2, const float* __restrict__ np2, const float* __restrict__ nn2,
    const float* __restrict__ s_w1, const float* __restrict__ s_b1,
    const float* __restrict__ s_w2,
    float* __restrict__ psum, float* __restrict__ Spart)
{
    __shared__ float4 xs4[RD];        // 4 KB: rows 0..3 of x-rep, per r
    __shared__ float4 cmbA[SH];       // 2 KB: A+b1 rows 0..3
    __shared__ float2 cmbW[SH];       // 1 KB: {wn, 0.5*w2}
    __shared__ float pda[2][128];     // stride-4B partials (conflict-free)
    __shared__ float pdb[2][128];
    __shared__ float pdc[2][128];
    __shared__ float pdd[2][128];
    __shared__ float ny2v[128];
    __shared__ float4 evb4[128];      // 2 KB: per-m {ev0..ev3}
    __shared__ float ssum[2][4];      // [m-half][row]
    const int t = threadIdx.x;
    const int set = blockIdx.x >> 9;
    const int rem = blockIdx.x & 511;
    const int n0 = (rem >> 2) << 2;
    const int mt = rem & 3;
    const int mbase = mt << 7;
    const int tm = t & 127, kh = t >> 7;   // kh uniform per wave
    const int m = mbase + tm;
    const float* yT = set ? rT_n : rT_p;
    const float* BT = set ? BT_n : BT_p;

    xs4[t] = make_float4(r_x[n0*RD + t],       r_x[(n0+1)*RD + t],
                         r_x[(n0+2)*RD + t],   r_x[(n0+3)*RD + t]);
    if (t < SH){
        const float b1v = s_b1[t];
        cmbA[t] = make_float4(A_x[n0*SH + t] + b1v,     A_x[(n0+1)*SH + t] + b1v,
                              A_x[(n0+2)*SH + t] + b1v, A_x[(n0+3)*SH + t] + b1v);
        cmbW[t] = make_float2(s_w1[768*SH + t], 0.5f * s_w2[t]);
        ny2v[t] = (set ? nn2 : np2)[mbase + t];
    }
    const float nxa = nx2[n0];         // wave-uniform -> scalar loads
    const float nxb = nx2[n0 + 1];
    const float nxc = nx2[n0 + 2];
    const float nxd = nx2[n0 + 3];
    __syncthreads();

    // phase 1: 4 dots over this wave's r-half (coalesced column-major loads)
    float d0=0.f, d1=0.f, d2=0.f, d3=0.f;
    {
        const float* yp = yT + (kh << 7)*NN + m;
        #pragma unroll 8
        for (int rr=0; rr<128; rr++){
            const float y = yp[rr*NN];
            const float4 xv = xs4[(kh << 7) + rr];   // b128 broadcast
            d0 = fmaf(xv.x, y, d0);
            d1 = fmaf(xv.y, y, d1);
            d2 = fmaf(xv.z, y, d2);
            d3 = fmaf(xv.w, y, d3);
        }
    }
    pda[kh][tm] = d0; pdb[kh][tm] = d1; pdc[kh][tm] = d2; pdd[kh][tm] = d3;
    __syncthreads();
    d0 += pda[1-kh][tm]; d1 += pdb[1-kh][tm];
    d2 += pdc[1-kh][tm]; d3 += pdd[1-kh][tm];
    const float nyc = ny2v[tm];
    const float dn0 = sqrtf(fmaxf(fmaf(-2.f, d0, nxa + nyc), 0.f));
    const float dn1 = sqrtf(fmaxf(fmaf(-2.f, d1, nxb + nyc), 0.f));
    const float dn2 = sqrtf(fmaxf(fmaf(-2.f, d2, nxc + nyc), 0.f));
    const float dn3 = sqrtf(fmaxf(fmaf(-2.f, d3, nxd + nyc), 0.f));

    // phase 2: logits over this wave's k-half (coalesced BT loads)
    float a0=0.f, a1=0.f, a2=0.f, a3=0.f;
    {
        const float* bp = BT + (kh << 6)*NN + m;
        #pragma unroll 4
        for (int kk=0; kk<64; kk++){
            const float b = bp[kk*NN];
            const float4 cA = cmbA[(kh << 6) + kk];   // b128 broadcast
            const float2 w  = cmbW[(kh << 6) + kk];   // b64 broadcast
            a0 = fmaf(w.y, gelu2(fmaf(dn0, w.x, cA.x + b)), a0);
            a1 = fmaf(w.y, gelu2(fmaf(dn1, w.x, cA.y + b)), a1);
            a2 = fmaf(w.y, gelu2(fmaf(dn2, w.x, cA.z + b)), a2);
            a3 = fmaf(w.y, gelu2(fmaf(dn3, w.x, cA.w + b)), a3);
        }
    }
    __syncthreads();                       // partner done reading phase-1 pd
    pda[kh][tm] = a0; pdb[kh][tm] = a1; pdc[kh][tm] = a2; pdd[kh][tm] = a3;
    __syncthreads();
    if (kh == 0){
        // s_b2 omitted (softmax shift-invariant); no max pass (logits O(1))
        const float L2E = 1.4426950408889634f;
        const float ev0 = __builtin_amdgcn_exp2f((a0 + pda[1][tm]) * L2E);
        const float ev1 = __builtin_amdgcn_exp2f((a1 + pdb[1][tm]) * L2E);
        const float ev2 = __builtin_amdgcn_exp2f((a2 + pdc[1][tm]) * L2E);
        const float ev3 = __builtin_amdgcn_exp2f((a3 + pdd[1][tm]) * L2E);
        evb4[tm] = make_float4(ev0, ev1, ev2, ev3);
        float v0 = ev0, v1 = ev1, v2 = ev2, v3 = ev3;
        #pragma unroll
        for (int off=32; off>=1; off>>=1){
            v0 += __shfl_xor(v0, off); v1 += __shfl_xor(v1, off);
            v2 += __shfl_xor(v2, off); v3 += __shfl_xor(v3, off);
        }
        if ((t & 63) == 0){
            const int mh = tm >> 6;
            ssum[mh][0] = v0; ssum[mh][1] = v1; ssum[mh][2] = v2; ssum[mh][3] = v3;
        }
    }
    __syncthreads();
    if (t < 4)
        Spart[(set*4 + mt)*NN + n0 + t] = ssum[0][t] + ssum[1][t];

    // fused partial einsum: psum[set][mt][n0+j][c] = Sum_{m in tile} ev_j * r_y[m][c]
    {
        const float* ry = (set ? r_n : r_p) + mbase*RD + t;   // coalesced in c=t
        float e0 = 0.f, e1 = 0.f, e2 = 0.f, e3 = 0.f;
        #pragma unroll 8
        for (int mm=0; mm<128; mm++){
            const float rv = ry[mm*RD];
            const float4 w = evb4[mm];       // b128 broadcast
            e0 = fmaf(w.x, rv, e0);
            e1 = fmaf(w.y, rv, e1);
            e2 = fmaf(w.z, rv, e2);
            e3 = fmaf(w.w, rv, e3);
        }
        float* P = psum + ((set*4 + mt)*NN + n0)*RD;
        P[t]        = e0;
        P[RD + t]   = e1;
        P[2*RD + t] = e2;
        P[3*RD + t] = e3;
    }
}

// K_FIN: dv = Sum_mt psum_p/Sp - Sum_mt psum_n/Sn; out = dv @ out_w.
// 1024 blocks (256 n-pairs x 4 col-tiles) x 256 thr = 4/CU, 16 waves/CU.
__global__ __launch_bounds__(256) void k_fin(
    const float* __restrict__ psum, const float* __restrict__ Spart,
    const float* __restrict__ out_w, float* __restrict__ out)
{
    __shared__ float dv[2][RD];   // 2 KB
    const int t = threadIdx.x;
    const int np = blockIdx.x >> 2, ct = blockIdx.x & 3;
    const int n0 = np << 1;
    const int cb = ct << 7;

    #pragma unroll
    for (int rep=0; rep<2; rep++){   // dv: 512 entries, 2/thread
        const int idx = rep*256 + t;
        const int j = idx >> 8, c = idx & 255;
        const int n = n0 + j;
        float Sp = 0.f, Sn = 0.f;
        #pragma unroll
        for (int q=0;q<4;q++){
            Sp += Spart[q*NN + n];
            Sn += Spart[(4+q)*NN + n];
        }
        float vp = 0.f, vn = 0.f;
        #pragma unroll
        for (int q=0;q<4;q++){
            vp += psum[(q*NN + n)*RD + c];
            vn += psum[((4+q)*NN + n)*RD + c];
        }
        dv[j][c] = vp * (1.0f/Sp) - vn * (1.0f/Sn);
    }
    __syncthreads();

    {   // out[j][cb+cc] = Sum_r dv[j][r]*out_w[r][cb+cc]
        const int j = t >> 7, cc = t & 127;
        const int col = cb + cc;
        float o = 0.f;
        const float* wo = out_w + col;
        #pragma unroll 8
        for (int r=0; r<RD; r++){ o = fmaf(dv[j][r], *wo, o); wo += IN; }
        out[(n0+j)*IN + col] = o;
    }
}

extern "C" void kernel_launch(void* const* d_in, const int* in_sizes, int n_in,
                              void* d_out, int out_size, void* d_ws, size_t ws_size,
                              hipStream_t stream)
{
    const float* fx  = (const float*)d_in[0];
    const float* fp  = (const float*)d_in[1];
    const float* fn  = (const float*)d_in[2];
    const float* gw1 = (const float*)d_in[3];
    const float* gb1 = (const float*)d_in[4];
    const float* gw2 = (const float*)d_in[5];
    const float* gb2 = (const float*)d_in[6];
    const float* ow  = (const float*)d_in[7];
    const float* sw1 = (const float*)d_in[8];
    const float* sb1 = (const float*)d_in[9];
    const float* sw2 = (const float*)d_in[10];
    float* out = (float*)d_out;

    float* ws   = (float*)d_ws;
    float* r_x  = ws;               // 512*256 row-major
    float* r_p  = r_x  + 131072;
    float* r_n  = r_p  + 131072;
    float* rT_p = r_n  + 131072;    // 256*512 column-major
    float* rT_n = rT_p + 131072;
    float* A_x  = rT_n + 131072;    // 512*128 row-major [n][k]
    float* BT_p = A_x  + 65536;     // 128*512 column-major [k][m]
    float* BT_n = BT_p + 65536;
    float* Spar = BT_n + 65536;     // 2*4*512
    float* nx2  = Spar + 4096;      // 512
    float* np2  = nx2  + 512;
    float* nn2  = np2  + 512;
    float* psum = nn2  + 512;       // 2*4*512*256 (4 MB)

    hipLaunchKernelGGL(k_rep, dim3(384), dim3(512), 0, stream,
                       fx, fp, fn, gw1, gb1, gw2, gb2, sw1,
                       r_x, r_p, r_n, rT_p, rT_n, A_x, BT_p, BT_n,
                       nx2, np2, nn2);
    hipLaunchKernelGGL(k_sd, dim3(1024), dim3(256), 0, stream,
                       r_x, rT_p, rT_n, A_x, BT_p, BT_n, r_p, r_n,
                       nx2, np2, nn2, sw1, sb1, sw2, psum, Spar);
    hipLaunchKernelGGL(k_fin, dim3(1024), dim3(256), 0, stream,
                       psum, Spar, ow, out);
}

// Round 17
// 153.898 us; speedup vs baseline: 2.4283x; 1.0141x over previous
//
#include <hip/hip_runtime.h>
#include <math.h>

#define NN 512   // set size / rows of feat_x
#define IN 512   // INPUT_DIM
#define HD 256   // HIDDEN_DIM
#define RD 256   // REP_DIM
#define SH 128   // SCORE_HIDDEN

// Branchless erf-GELU, A&S 7.1.26 (5-term) -- used in the g-MLP hidden layer.
__device__ __forceinline__ float gelu_fast(float x){
    const float z  = x * 0.70710678118654752f;
    const float az = fabsf(z);
    const float t  = __builtin_amdgcn_rcpf(fmaf(0.3275911f, az, 1.0f));
    float p = fmaf(1.061405429f, t, -1.453152027f);
    p = fmaf(p, t, 1.421413741f);
    p = fmaf(p, t, -0.284496736f);
    p = fmaf(p, t, 0.254829592f);
    p = p * t;
    const float e = __builtin_amdgcn_exp2f(z * z * -1.4426950408889634f);
    const float E = p * e;                        // erfc(|z|)
    const float one_plus_erf = (x >= 0.0f) ? (2.0f - E) : E;
    return 0.5f * x * one_plus_erf;
}

// u*(1+erf(u/sqrt2)) -- 0.5 folded into caller's weight. A&S 7.1.25 (3-term).
__device__ __forceinline__ float gelu2(float u){
    const float az = fabsf(u);
    const float tt = __builtin_amdgcn_rcpf(fmaf(0.3326725f, az, 1.0f));
    const float P  = fmaf(fmaf(0.7478556f, tt, -0.0958798f), tt, 0.3480242f) * tt;
    const float e2 = __builtin_amdgcn_exp2f(u * u * -0.72134752044448170f);
    const float Eq = P * e2;                      // erfc(|u|/sqrt2)
    const float ope = (u >= 0.0f) ? (2.0f - Eq) : Eq;
    return u * ope;
}

// K_REP: fused g-MLP + score-net projections + row norms (verbatim r15/r16
// winner: 4-row/512-thread/384-block).
__global__ __launch_bounds__(512) void k_rep(
    const float* __restrict__ fx, const float* __restrict__ fp, const float* __restrict__ fn,
    const float* __restrict__ w1, const float* __restrict__ b1,
    const float* __restrict__ w2, const float* __restrict__ b2,
    const float* __restrict__ s_w1,
    float* __restrict__ r_x, float* __restrict__ r_p, float* __restrict__ r_n,
    float* __restrict__ rT_p, float* __restrict__ rT_n,
    float* __restrict__ A_x, float* __restrict__ BT_p, float* __restrict__ BT_n,
    float* __restrict__ nx2, float* __restrict__ np2, float* __restrict__ nn2)
{
    __shared__ float xs[4][IN];        // 8 KB
    __shared__ float ps[8][4][HD];     // 32 KB partials (reused by all GEMM phases)
    __shared__ float hs[4][HD];        // 4 KB
    __shared__ float rloc[4][RD];      // 4 KB
    __shared__ float ab4[4][SH];       // 2 KB
    const int t = threadIdx.x;
    const int mat = blockIdx.x >> 7;
    const int row0 = (blockIdx.x & 127) << 2;
    const float* src = (mat==0) ? fx : (mat==1) ? fp : fn;

    {   // stage 4 feat rows: 512 float4s
        const int j = t >> 7, c4 = (t & 127) << 2;
        *(float4*)&xs[j][c4] = *(const float4*)&src[(row0+j)*IN + c4];
    }
    __syncthreads();

    const int cg = t & 63, s = t >> 6;   // 64 colgroups x 8 K-slices
    const int c0 = cg << 2;

    {   // GEMM1: K=512, slice [s*64, s*64+64)
        float4 acc[4];
        #pragma unroll
        for (int j=0;j<4;j++) acc[j] = make_float4(0.f,0.f,0.f,0.f);
        const float* wp = w1 + (s*64)*HD + c0;
        #pragma unroll 8
        for (int ii=0; ii<64; ii++){
            float4 w = *(const float4*)wp; wp += HD;
            const int i = s*64 + ii;
            #pragma unroll
            for (int j=0;j<4;j++){
                const float xv = xs[j][i];
                acc[j].x = fmaf(xv, w.x, acc[j].x);
                acc[j].y = fmaf(xv, w.y, acc[j].y);
                acc[j].z = fmaf(xv, w.z, acc[j].z);
                acc[j].w = fmaf(xv, w.w, acc[j].w);
            }
        }
        #pragma unroll
        for (int j=0;j<4;j++) *(float4*)&ps[s][j][c0] = acc[j];
    }
    __syncthreads();

    #pragma unroll
    for (int rep=0; rep<2; rep++){   // reduce + bias + GELU -> hs
        const int idx = rep*512 + t;
        const int j = idx >> 8, c = idx & 255;
        float v = b1[c];
        #pragma unroll
        for (int ss=0; ss<8; ss++) v += ps[ss][j][c];
        hs[j][c] = gelu_fast(v);
    }
    __syncthreads();

    {   // GEMM2: K=256, slice [s*32, s*32+32)
        float4 acc[4];
        #pragma unroll
        for (int j=0;j<4;j++) acc[j] = make_float4(0.f,0.f,0.f,0.f);
        const float* wp = w2 + (s*32)*RD + c0;
        #pragma unroll 8
        for (int ii=0; ii<32; ii++){
            float4 w = *(const float4*)wp; wp += RD;
            const int i = s*32 + ii;
            #pragma unroll
            for (int j=0;j<4;j++){
                const float xv = hs[j][i];
                acc[j].x = fmaf(xv, w.x, acc[j].x);
                acc[j].y = fmaf(xv, w.y, acc[j].y);
                acc[j].z = fmaf(xv, w.z, acc[j].z);
                acc[j].w = fmaf(xv, w.w, acc[j].w);
            }
        }
        #pragma unroll
        for (int j=0;j<4;j++) *(float4*)&ps[s][j][c0] = acc[j];
    }
    __syncthreads();

    float* rout = (mat==0) ? r_x : (mat==1) ? r_p : r_n;
    #pragma unroll
    for (int rep=0; rep<2; rep++){   // reduce + bias -> rloc + global r
        const int idx = rep*512 + t;
        const int j = idx >> 8, c = idx & 255;
        float v = b2[c];
        #pragma unroll
        for (int ss=0; ss<8; ss++) v += ps[ss][j][c];
        rloc[j][c] = v;
        rout[(row0+j)*RD + c] = v;
    }
    __syncthreads();   // rloc complete; ps free for reuse

    if (t < 256){   // squared row norms: waves 0..3 -> rows 0..3
        const int w = t >> 6, l = t & 63;
        float v = 0.f;
        #pragma unroll
        for (int q=0;q<4;q++){ const float e = rloc[w][l + 64*q]; v = fmaf(e,e,v); }
        #pragma unroll
        for (int off=32; off>=1; off>>=1) v += __shfl_xor(v, off);
        if (l==0){
            float* nrm = (mat==0) ? nx2 : (mat==1) ? np2 : nn2;
            nrm[row0 + w] = v;
        }
    }
    if (mat && t < 256){   // transposed rep copy rT[r][m], float4 across rows
        float* rT = (mat==1) ? rT_p : rT_n;
        float4 q = make_float4(rloc[0][t], rloc[1][t], rloc[2][t], rloc[3][t]);
        *(float4*)&rT[t*NN + row0] = q;
    }

    {   // score-net projection: 128 cols, K=256 in 16 slices of 16
        const int cg2 = t & 31, s2 = t >> 5;
        const int cc0 = cg2 << 2;
        const float sgn = (mat==0) ? -1.0f : 1.0f;
        const int base1 = (mat==0) ? 0 : 256;
        const float* p1 = s_w1 + (base1 + s2*16)*SH + cc0;
        const float* p3 = s_w1 + (512   + s2*16)*SH + cc0;
        float4 a[4];
        #pragma unroll
        for (int j=0;j<4;j++) a[j] = make_float4(0.f,0.f,0.f,0.f);
        #pragma unroll 8
        for (int ii=0; ii<16; ii++){
            float4 wa = *(const float4*)p1; p1 += SH;
            float4 wd = *(const float4*)p3; p3 += SH;
            float4 w;
            w.x = fmaf(sgn, wd.x, wa.x);
            w.y = fmaf(sgn, wd.y, wa.y);
            w.z = fmaf(sgn, wd.z, wa.z);
            w.w = fmaf(sgn, wd.w, wa.w);
            const int i = s2*16 + ii;
            #pragma unroll
            for (int j=0;j<4;j++){
                const float xv = rloc[j][i];
                a[j].x = fmaf(xv, w.x, a[j].x);
                a[j].y = fmaf(xv, w.y, a[j].y);
                a[j].z = fmaf(xv, w.z, a[j].z);
                a[j].w = fmaf(xv, w.w, a[j].w);
            }
        }
        float* psf = &ps[0][0][0];   // reuse as [16][4][128]
        #pragma unroll
        for (int j=0;j<4;j++) *(float4*)&psf[(s2*4 + j)*SH + cc0] = a[j];
    }
    __syncthreads();

    {   // reduce 16 slices: 4 rows x 128 cols = 512 outputs
        const float* psf = &ps[0][0][0];
        const int j = t >> 7, c = t & 127;
        float v = 0.f;
        #pragma unroll
        for (int ss=0; ss<16; ss++) v += psf[(ss*4 + j)*SH + c];
        if (mat==0) A_x[(row0+j)*SH + c] = v;
        else        ab4[j][c] = v;
    }
    __syncthreads();
    if (mat && t < 128){   // BT[k][m], float4 across rows
        float* BT = (mat==1) ? BT_p : BT_n;
        float4 q = make_float4(ab4[0][t], ab4[1][t], ab4[2][t], ab4[3][t]);
        *(float4*)&BT[t*NN + row0] = q;
    }
}

// K_SD: 4 rows/thread AND 32 waves/CU. 2048 blocks (set x 128 4-row ntiles
// x 8 64-m mtiles) x 256 thr = 8 blocks/CU. 4-way wave-level k-split
// (wave kh takes quarter kh of the r/k range); lanes sweep 64 consecutive
// m -> all loads coalesced; 4-way stride-4B LDS combine (conflict-free).
__global__ __launch_bounds__(256) void k_sd(
    const float* __restrict__ r_x, const float* __restrict__ rT_p, const float* __restrict__ rT_n,
    const float* __restrict__ A_x, const float* __restrict__ BT_p, const float* __restrict__ BT_n,
    const float* __restrict__ r_p, const float* __restrict__ r_n,
    const float* __restrict__ nx2, const float* __restrict__ np2, const float* __restrict__ nn2,
    const float* __restrict__ s_w1, const float* __restrict__ s_b1,
    const float* __restrict__ s_w2,
    float* __restrict__ psum, float* __restrict__ Spart)
{
    __shared__ float4 xs4[RD];        // 4 KB: rows 0..3 of x-rep, per r
    __shared__ float4 cmbA[SH];       // 2 KB: A+b1 rows 0..3
    __shared__ float2 cmbW[SH];       // 1 KB: {wn, 0.5*w2}
    __shared__ float pda[4][64];      // stride-4B partials (conflict-free)
    __shared__ float pdb[4][64];
    __shared__ float pdc[4][64];
    __shared__ float pdd[4][64];
    __shared__ float ny2v[64];
    __shared__ float4 evb4[64];       // 1 KB: per-m {ev0..ev3}
    const int t = threadIdx.x;
    const int set = blockIdx.x >> 10;
    const int rem = blockIdx.x & 1023;
    const int n0 = (rem >> 3) << 2;
    const int mt = rem & 7;
    const int mbase = mt << 6;
    const int tm = t & 63, kh = t >> 6;    // kh in {0..3}, uniform per wave
    const int m = mbase + tm;
    const float* yT = set ? rT_n : rT_p;
    const float* BT = set ? BT_n : BT_p;

    xs4[t] = make_float4(r_x[n0*RD + t],       r_x[(n0+1)*RD + t],
                         r_x[(n0+2)*RD + t],   r_x[(n0+3)*RD + t]);
    if (t < SH){
        const float b1v = s_b1[t];
        cmbA[t] = make_float4(A_x[n0*SH + t] + b1v,     A_x[(n0+1)*SH + t] + b1v,
                              A_x[(n0+2)*SH + t] + b1v, A_x[(n0+3)*SH + t] + b1v);
        cmbW[t] = make_float2(s_w1[768*SH + t], 0.5f * s_w2[t]);
    }
    if (t < 64) ny2v[t] = (set ? nn2 : np2)[mbase + t];
    const float nxa = nx2[n0];         // wave-uniform -> scalar loads
    const float nxb = nx2[n0 + 1];
    const float nxc = nx2[n0 + 2];
    const float nxd = nx2[n0 + 3];
    __syncthreads();

    // phase 1: 4 dots over this wave's r-quarter (coalesced column-major)
    float d0=0.f, d1=0.f, d2=0.f, d3=0.f;
    {
        const float* yp = yT + (kh << 6)*NN + m;
        #pragma unroll 8
        for (int rr=0; rr<64; rr++){
            const float y = yp[rr*NN];
            const float4 xv = xs4[(kh << 6) + rr];   // b128 broadcast
            d0 = fmaf(xv.x, y, d0);
            d1 = fmaf(xv.y, y, d1);
            d2 = fmaf(xv.z, y, d2);
            d3 = fmaf(xv.w, y, d3);
        }
    }
    pda[kh][tm] = d0; pdb[kh][tm] = d1; pdc[kh][tm] = d2; pdd[kh][tm] = d3;
    __syncthreads();
    d0 = pda[0][tm] + pda[1][tm] + pda[2][tm] + pda[3][tm];
    d1 = pdb[0][tm] + pdb[1][tm] + pdb[2][tm] + pdb[3][tm];
    d2 = pdc[0][tm] + pdc[1][tm] + pdc[2][tm] + pdc[3][tm];
    d3 = pdd[0][tm] + pdd[1][tm] + pdd[2][tm] + pdd[3][tm];
    const float nyc = ny2v[tm];
    const float dn0 = sqrtf(fmaxf(fmaf(-2.f, d0, nxa + nyc), 0.f));
    const float dn1 = sqrtf(fmaxf(fmaf(-2.f, d1, nxb + nyc), 0.f));
    const float dn2 = sqrtf(fmaxf(fmaf(-2.f, d2, nxc + nyc), 0.f));
    const float dn3 = sqrtf(fmaxf(fmaf(-2.f, d3, nxd + nyc), 0.f));

    // phase 2: logits over this wave's k-quarter (coalesced BT loads)
    float a0=0.f, a1=0.f, a2=0.f, a3=0.f;
    {
        const float* bp = BT + (kh << 5)*NN + m;
        #pragma unroll 4
        for (int kk=0; kk<32; kk++){
            const float b = bp[kk*NN];
            const float4 cA = cmbA[(kh << 5) + kk];   // b128 broadcast
            const float2 w  = cmbW[(kh << 5) + kk];   // b64 broadcast
            a0 = fmaf(w.y, gelu2(fmaf(dn0, w.x, cA.x + b)), a0);
            a1 = fmaf(w.y, gelu2(fmaf(dn1, w.x, cA.y + b)), a1);
            a2 = fmaf(w.y, gelu2(fmaf(dn2, w.x, cA.z + b)), a2);
            a3 = fmaf(w.y, gelu2(fmaf(dn3, w.x, cA.w + b)), a3);
        }
    }
    __syncthreads();                       // all waves done reading phase-1 pd
    pda[kh][tm] = a0; pdb[kh][tm] = a1; pdc[kh][tm] = a2; pdd[kh][tm] = a3;
    __syncthreads();
    if (kh == 0){   // wave 0: combine, exp, stage ev, tile row sums
        // s_b2 omitted (softmax shift-invariant); no max pass (logits O(1))
        const float L2E = 1.4426950408889634f;
        const float l0 = pda[0][tm]+pda[1][tm]+pda[2][tm]+pda[3][tm];
        const float l1 = pdb[0][tm]+pdb[1][tm]+pdb[2][tm]+pdb[3][tm];
        const float l2 = pdc[0][tm]+pdc[1][tm]+pdc[2][tm]+pdc[3][tm];
        const float l3 = pdd[0][tm]+pdd[1][tm]+pdd[2][tm]+pdd[3][tm];
        const float ev0 = __builtin_amdgcn_exp2f(l0 * L2E);
        const float ev1 = __builtin_amdgcn_exp2f(l1 * L2E);
        const float ev2 = __builtin_amdgcn_exp2f(l2 * L2E);
        const float ev3 = __builtin_amdgcn_exp2f(l3 * L2E);
        evb4[tm] = make_float4(ev0, ev1, ev2, ev3);
        float v0 = ev0, v1 = ev1, v2 = ev2, v3 = ev3;
        #pragma unroll
        for (int off=32; off>=1; off>>=1){
            v0 += __shfl_xor(v0, off); v1 += __shfl_xor(v1, off);
            v2 += __shfl_xor(v2, off); v3 += __shfl_xor(v3, off);
        }
        if (tm == 0){
            float* Sp = Spart + (set*8 + mt)*NN + n0;
            Sp[0] = v0; Sp[1] = v1; Sp[2] = v2; Sp[3] = v3;
        }
    }
    __syncthreads();

    // fused partial einsum: psum[set][mt][n0+j][c] = Sum_{m in tile} ev_j * r_y[m][c]
    {
        const float* ry = (set ? r_n : r_p) + mbase*RD + t;   // coalesced in c=t
        float e0 = 0.f, e1 = 0.f, e2 = 0.f, e3 = 0.f;
        #pragma unroll 8
        for (int mm=0; mm<64; mm++){
            const float rv = ry[mm*RD];
            const float4 w = evb4[mm];       // b128 broadcast
            e0 = fmaf(w.x, rv, e0);
            e1 = fmaf(w.y, rv, e1);
            e2 = fmaf(w.z, rv, e2);
            e3 = fmaf(w.w, rv, e3);
        }
        float* P = psum + ((set*8 + mt)*NN + n0)*RD;
        P[t]        = e0;
        P[RD + t]   = e1;
        P[2*RD + t] = e2;
        P[3*RD + t] = e3;
    }
}

// K_FIN: dv = Sum_mt psum_p/Sp - Sum_mt psum_n/Sn (8 mt slices); out = dv @ out_w.
// 1024 blocks (256 n-pairs x 4 col-tiles) x 256 thr = 4/CU, 16 waves/CU.
__global__ __launch_bounds__(256) void k_fin(
    const float* __restrict__ psum, const float* __restrict__ Spart,
    const float* __restrict__ out_w, float* __restrict__ out)
{
    __shared__ float dv[2][RD];   // 2 KB
    const int t = threadIdx.x;
    const int np = blockIdx.x >> 2, ct = blockIdx.x & 3;
    const int n0 = np << 1;
    const int cb = ct << 7;

    #pragma unroll
    for (int rep=0; rep<2; rep++){   // dv: 512 entries, 2/thread
        const int idx = rep*256 + t;
        const int j = idx >> 8, c = idx & 255;
        const int n = n0 + j;
        float Sp = 0.f, Sn = 0.f;
        #pragma unroll
        for (int q=0;q<8;q++){
            Sp += Spart[q*NN + n];
            Sn += Spart[(8+q)*NN + n];
        }
        float vp = 0.f, vn = 0.f;
        #pragma unroll
        for (int q=0;q<8;q++){
            vp += psum[(q*NN + n)*RD + c];
            vn += psum[((8+q)*NN + n)*RD + c];
        }
        dv[j][c] = vp * (1.0f/Sp) - vn * (1.0f/Sn);
    }
    __syncthreads();

    {   // out[j][cb+cc] = Sum_r dv[j][r]*out_w[r][cb+cc]
        const int j = t >> 7, cc = t & 127;
        const int col = cb + cc;
        float o = 0.f;
        const float* wo = out_w + col;
        #pragma unroll 8
        for (int r=0; r<RD; r++){ o = fmaf(dv[j][r], *wo, o); wo += IN; }
        out[(n0+j)*IN + col] = o;
    }
}

extern "C" void kernel_launch(void* const* d_in, const int* in_sizes, int n_in,
                              void* d_out, int out_size, void* d_ws, size_t ws_size,
                              hipStream_t stream)
{
    const float* fx  = (const float*)d_in[0];
    const float* fp  = (const float*)d_in[1];
    const float* fn  = (const float*)d_in[2];
    const float* gw1 = (const float*)d_in[3];
    const float* gb1 = (const float*)d_in[4];
    const float* gw2 = (const float*)d_in[5];
    const float* gb2 = (const float*)d_in[6];
    const float* ow  = (const float*)d_in[7];
    const float* sw1 = (const float*)d_in[8];
    const float* sb1 = (const float*)d_in[9];
    const float* sw2 = (const float*)d_in[10];
    float* out = (float*)d_out;

    float* ws   = (float*)d_ws;
    float* r_x  = ws;               // 512*256 row-major
    float* r_p  = r_x  + 131072;
    float* r_n  = r_p  + 131072;
    float* rT_p = r_n  + 131072;    // 256*512 column-major
    float* rT_n = rT_p + 131072;
    float* A_x  = rT_n + 131072;    // 512*128 row-major [n][k]
    float* BT_p = A_x  + 65536;     // 128*512 column-major [k][m]
    float* BT_n = BT_p + 65536;
    float* Spar = BT_n + 65536;     // 2*8*512
    float* nx2  = Spar + 8192;      // 512
    float* np2  = nx2  + 512;
    float* nn2  = np2  + 512;
    float* psum = nn2  + 512;       // 2*8*512*256 (8 MB)

    hipLaunchKernelGGL(k_rep, dim3(384), dim3(512), 0, stream,
                       fx, fp, fn, gw1, gb1, gw2, gb2, sw1,
                       r_x, r_p, r_n, rT_p, rT_n, A_x, BT_p, BT_n,
                       nx2, np2, nn2);
    hipLaunchKernelGGL(k_sd, dim3(2048), dim3(256), 0, stream,
                       r_x, rT_p, rT_n, A_x, BT_p, BT_n, r_p, r_n,
                       nx2, np2, nn2, sw1, sb1, sw2, psum, Spar);
    hipLaunchKernelGGL(k_fin, dim3(1024), dim3(256), 0, stream,
                       psum, Spar, ow, out);
}